// Round 7
// baseline (101.234 us; speedup 1.0000x reference)
//
#include <hip/hip_runtime.h>

// MultiScaleGeometricAttention: B=8, T=2048, D=512, N=4096 (f32 in/out).
//
// With ages=0, attention_scale = 0.05 exactly, so effective_temp =
// (|temp|+0.1)*0.05 ≈ 0.03.  dist(x,p) ≈ 25.3 for this distribution, so every
// weight is exp(-~843), which underflows to EXACTLY 0 in f32 (underflow at
// arg ≈ -104).  Row sum = 0, denominator = 1e-8, output ≡ 0.  Validated
// rounds 1 & 5 (passed, absmax=0).
//
// Per row we PROVE underflow:  dist(x,p_n) >= ||x|| - max||p||  (reverse
// triangle ineq.), so  ||x||^2 > (max||p|| + 106*max_temp)^2  =>  every
// exp underflows to exactly 0.  Rows failing the proof take an exact
// per-wave fallback (never executes on this data; margin ~7.2 vs ~3.18).
//
// R1 lesson: same-address atomicMax serialized (~12ns each, 96us) — use
// per-block max slots.  R5 lesson: timed graph is dominated by the
// harness's 268MB ws re-poison fill (~41us) + input restore (~16us) +
// out fill (~5us); our kernels are ~30us of 96.8.  This round: hoist the
// 256-maxima reduce into a 1-wave kernel producing one scalar thr2, and
// give rows 2 independent rows/wave for ILP, shortening the per-wave
// dependent chain before the zero stores.

#define DDIM 512
#define NPOS 4096
#define PBLK 256   // pstats grid size
#define TPB  256

// ws layout (floats):
//   [0 .. PBLK)                     per-block max ||p||^2
//   [PBLK .. 2*PBLK)                per-block max eff_temp
//   [2*PBLK .. 2*PBLK+NPOS)         ||p_n||^2          (fallback only)
//   [2*PBLK+NPOS .. 2*PBLK+2*NPOS)  eff_temp_n         (fallback only)
//   [2*PBLK+2*NPOS]                 thr2 scalar
#define THR2_OFF (2 * PBLK + 2 * NPOS)

__global__ __launch_bounds__(TPB) void msga_pstats(
    const float* __restrict__ P, const float* __restrict__ temp,
    float* __restrict__ ws) {
    const int b    = blockIdx.x;
    const int t    = threadIdx.x;
    const int wave = t >> 6;
    const int lane = t & 63;
    __shared__ float pmS[TPB / 64], tmS[TPB / 64];

    float pm = 0.f, tm = 0.f;  // tracked on lane 0 of each wave
#pragma unroll
    for (int i = 0; i < NPOS / PBLK / (TPB / 64); ++i) {  // 4 rows per wave
        const int n = b * (NPOS / PBLK) + wave * 4 + i;
        const float4* p = reinterpret_cast<const float4*>(P + (size_t)n * DDIM);
        const float4 a = p[lane];        // coalesced: 64 lanes x 16B = row half
        const float4 c = p[lane + 64];
        float s = a.x * a.x + a.y * a.y + a.z * a.z + a.w * a.w
                + c.x * c.x + c.y * c.y + c.z * c.z + c.w * c.w;
#pragma unroll
        for (int off = 32; off > 0; off >>= 1) s += __shfl_xor(s, off, 64);
        if (lane == 0) {
            ws[2 * PBLK + n] = s;
            const float te = (fabsf(temp[n]) + 0.1f) * 0.05f;
            ws[2 * PBLK + NPOS + n] = te;
            pm = fmaxf(pm, s);
            tm = fmaxf(tm, te);
        }
    }
    if (lane == 0) { pmS[wave] = pm; tmS[wave] = tm; }
    __syncthreads();
    if (t == 0) {
        float bp = pmS[0], bt = tmS[0];
#pragma unroll
        for (int w = 1; w < TPB / 64; ++w) {
            bp = fmaxf(bp, pmS[w]);
            bt = fmaxf(bt, tmS[w]);
        }
        ws[b]        = bp;   // per-block max ||p||^2
        ws[PBLK + b] = bt;   // per-block max eff_temp
    }
}

// 1 wave: reduce the 2x256 per-block maxima to one scalar threshold.
// ||x||^2 > thr2  <=>  ||x|| - max||p|| > 106*max_temp  (all nonneg).
__global__ void msga_thresh(float* __restrict__ ws) {
    const int lane = threadIdx.x & 63;
    float pm = fmaxf(fmaxf(ws[lane], ws[lane + 64]),
                     fmaxf(ws[lane + 128], ws[lane + 192]));
    float tm = fmaxf(fmaxf(ws[PBLK + lane], ws[PBLK + lane + 64]),
                     fmaxf(ws[PBLK + lane + 128], ws[PBLK + lane + 192]));
#pragma unroll
    for (int off = 32; off > 0; off >>= 1) {
        pm = fmaxf(pm, __shfl_xor(pm, off, 64));
        tm = fmaxf(tm, __shfl_xor(tm, off, 64));
    }
    if (lane == 0) {
        const float r = sqrtf(pm) + 106.0f * tm;
        ws[THR2_OFF] = r * r;
    }
}

// Exact per-wave fallback for one row (never taken for this distribution).
__device__ __noinline__ void msga_row_exact(
    const float* __restrict__ P, const float* __restrict__ V,
    const float* __restrict__ ws, float* __restrict__ orow,
    float4 xa, float4 xb, float xn2, int lane) {
    const float* pnorm2 = ws + 2 * PBLK;
    const float* teff   = ws + 2 * PBLK + NPOS;
    float4 aa = make_float4(0.f, 0.f, 0.f, 0.f);
    float4 ab = make_float4(0.f, 0.f, 0.f, 0.f);
    float wsum = 0.f;
    for (int n = 0; n < NPOS; ++n) {
        const float4* pr = reinterpret_cast<const float4*>(P + (size_t)n * DDIM);
        const float4 pa = pr[lane];
        const float4 pb = pr[lane + 64];
        float d = xa.x * pa.x + xa.y * pa.y + xa.z * pa.z + xa.w * pa.w
                + xb.x * pb.x + xb.y * pb.y + xb.z * pb.z + xb.w * pb.w;
#pragma unroll
        for (int off = 32; off > 0; off >>= 1) d += __shfl_xor(d, off, 64);
        const float dist = sqrtf(fmaxf(xn2 + pnorm2[n] - 2.f * d, 0.f));
        const float w    = expf(-dist / teff[n]);
        wsum += w;
        const float4* vr = reinterpret_cast<const float4*>(V + (size_t)n * DDIM);
        const float4 va = vr[lane];
        const float4 vb = vr[lane + 64];
        aa.x += w * va.x; aa.y += w * va.y; aa.z += w * va.z; aa.w += w * va.w;
        ab.x += w * vb.x; ab.y += w * vb.y; ab.z += w * vb.z; ab.w += w * vb.w;
    }
    const float inv = 1.0f / (wsum + 1e-8f);
    aa.x *= inv; aa.y *= inv; aa.z *= inv; aa.w *= inv;
    ab.x *= inv; ab.y *= inv; ab.z *= inv; ab.w *= inv;
    reinterpret_cast<float4*>(orow)[lane]      = aa;
    reinterpret_cast<float4*>(orow)[lane + 64] = ab;
}

__global__ __launch_bounds__(TPB) void msga_rows(
    const float* __restrict__ X, const float* __restrict__ P,
    const float* __restrict__ V, const float* __restrict__ ws,
    float* __restrict__ out, int half_rows) {
    const int t    = threadIdx.x;
    const int wave = t >> 6;
    const int lane = t & 63;
    const int row0 = blockIdx.x * (TPB / 64) + wave;  // two rows per wave
    const int row1 = row0 + half_rows;

    const float thr2 = ws[THR2_OFF];  // wave-uniform scalar

    // two independent row loads: 8 floats/lane each, coalesced float4
    const float4* xr0 = reinterpret_cast<const float4*>(X + (size_t)row0 * DDIM);
    const float4* xr1 = reinterpret_cast<const float4*>(X + (size_t)row1 * DDIM);
    const float4 xa0 = xr0[lane];
    const float4 xb0 = xr0[lane + 64];
    const float4 xa1 = xr1[lane];
    const float4 xb1 = xr1[lane + 64];
    float s0 = xa0.x * xa0.x + xa0.y * xa0.y + xa0.z * xa0.z + xa0.w * xa0.w
             + xb0.x * xb0.x + xb0.y * xb0.y + xb0.z * xb0.z + xb0.w * xb0.w;
    float s1 = xa1.x * xa1.x + xa1.y * xa1.y + xa1.z * xa1.z + xa1.w * xa1.w
             + xb1.x * xb1.x + xb1.y * xb1.y + xb1.z * xb1.z + xb1.w * xb1.w;
#pragma unroll
    for (int off = 32; off > 0; off >>= 1) {  // paired reduce, independent chains
        s0 += __shfl_xor(s0, off, 64);
        s1 += __shfl_xor(s1, off, 64);
    }

    float4* o0 = reinterpret_cast<float4*>(out + (size_t)row0 * DDIM);
    float4* o1 = reinterpret_cast<float4*>(out + (size_t)row1 * DDIM);
    const bool z0 = s0 > thr2;
    const bool z1 = s1 > thr2;
    const float4 z = make_float4(0.f, 0.f, 0.f, 0.f);
    if (z0) { o0[lane] = z; o0[lane + 64] = z; }
    if (z1) { o1[lane] = z; o1[lane + 64] = z; }
    if (z0 & z1) return;

    // ---- exact fallback (never taken for this distribution) ----
    if (!z0) msga_row_exact(P, V, ws, (float*)o0, xa0, xb0, s0, lane);
    if (!z1) msga_row_exact(P, V, ws, (float*)o1, xa1, xb1, s1, lane);
}

extern "C" void kernel_launch(void* const* d_in, const int* in_sizes, int n_in,
                              void* d_out, int out_size, void* d_ws, size_t ws_size,
                              hipStream_t stream) {
    const float* X    = (const float*)d_in[0];
    const float* P    = (const float*)d_in[1];
    const float* V    = (const float*)d_in[2];
    const float* temp = (const float*)d_in[3];
    float* out = (float*)d_out;
    float* ws  = (float*)d_ws;
    const int rows      = in_sizes[0] / DDIM;  // B*T = 16384
    const int half_rows = rows / 2;

    msga_pstats<<<PBLK, TPB, 0, stream>>>(P, temp, ws);
    msga_thresh<<<1, 64, 0, stream>>>(ws);
    msga_rows<<<half_rows / (TPB / 64), TPB, 0, stream>>>(X, P, V, ws, out,
                                                          half_rows);
}